// Round 5
// baseline (295.761 us; speedup 1.0000x reference)
//
#include <hip/hip_runtime.h>
#include <hip/hip_bf16.h>
#include <stdint.h>

#define DIM 512
#define NROWS 1024
#define NCLS 70722
#define NC16 4421                   // ceil(70722/16) 16-class groups (0..4420)
// 277 c-tiles of 256 cols; 32 c-groups: cgrp<21 own 9 tiles, else 8 (stride-32)

typedef float floatx4 __attribute__((ext_vector_type(4)));

// pack 4 floats -> 4 OCP e4m3 bytes (HW cvt, RNE+sat)
__device__ __forceinline__ unsigned pk4_fp8(float a, float b, float c, float d) {
    unsigned v = 0;
    v = __builtin_amdgcn_cvt_pk_fp8_f32(a, b, v, false);  // low 16 bits
    v = __builtin_amdgcn_cvt_pk_fp8_f32(c, d, v, true);   // high 16 bits
    return v;
}

__device__ __forceinline__ float wave_reduce_sum(float s) {
    #pragma unroll
    for (int m = 1; m < 64; m <<= 1) s += __shfl_xor(s, m);
    return s;
}

// --- kernel 1: fused prep, FRAGMENT-TRANSPOSED outputs -----------------------
// Layout: 8B k-slot j (bytes [8j,8j+8) of the normalized fp8 row) of class/row
// r lives at base + (r>>4)*8192 + j*128 + (r&15)*8. A wave's GEMM fragment
// load (lane=(fr,fq), slot kslot*4+fq, rows g*16+fr) is then 512B contiguous.
// blocks [0,256):  x rows (4/block, wave-per-row) -> AnT, rownorm, coslab, rowsum=0
// blocks [256,..): W 16-class groups (4/block, wave-per-group) -> WT
__global__ __launch_bounds__(256) void prep_kernel(
        const float* __restrict__ x, const float* __restrict__ W,
        const int* __restrict__ labels,
        uint8_t* __restrict__ AnT, uint8_t* __restrict__ WT,
        float* __restrict__ rownorm, float* __restrict__ coslab,
        float* __restrict__ rowsum) {
    int b = blockIdx.x;
    int wv = threadIdx.x >> 6, lane = threadIdx.x & 63;
    if (b < NROWS / 4) {
        if (threadIdx.x < 4) rowsum[b * 4 + threadIdx.x] = 0.0f;
        int row = b * 4 + wv;
        int lab = labels[row];
        const float4* xs = (const float4*)(x + (size_t)row * DIM);
        const float4* ws = (const float4*)(W + (size_t)lab * DIM);
        float4 xa = xs[lane * 2], xb = xs[lane * 2 + 1];
        float4 wa = ws[lane * 2], wb = ws[lane * 2 + 1];
        float dxx = xa.x*xa.x + xa.y*xa.y + xa.z*xa.z + xa.w*xa.w
                  + xb.x*xb.x + xb.y*xb.y + xb.z*xb.z + xb.w*xb.w;
        float dww = wa.x*wa.x + wa.y*wa.y + wa.z*wa.z + wa.w*wa.w
                  + wb.x*wb.x + wb.y*wb.y + wb.z*wb.z + wb.w*wb.w;
        float dxw = xa.x*wa.x + xa.y*wa.y + xa.z*wa.z + xa.w*wa.w
                  + xb.x*wb.x + xb.y*wb.y + xb.z*wb.z + xb.w*wb.w;
        dxx = wave_reduce_sum(dxx);
        dww = wave_reduce_sum(dww);
        dxw = wave_reduce_sum(dxw);
        float norm = sqrtf(dxx);
        float s16 = 16.0f / fmaxf(norm, 1e-12f);
        uint2 p;
        p.x = pk4_fp8(xa.x*s16, xa.y*s16, xa.z*s16, xa.w*s16);
        p.y = pk4_fp8(xb.x*s16, xb.y*s16, xb.z*s16, xb.w*s16);
        // transposed store: lane holds k-slot = lane (elements [8*lane, 8*lane+8))
        *(uint2*)(AnT + (size_t)(row >> 4) * 8192 + lane * 128 + (row & 15) * 8) = p;
        if (lane == 0) {
            rownorm[row] = norm;
            coslab[row]  = dxw / (fmaxf(norm, 1e-12f) * fmaxf(sqrtf(dww), 1e-12f));
        }
    } else {
        // wave per 16-class group: after 16 classes, lane holds the full 128B
        // output row [kslot=lane][fr=0..15] -> 8 contiguous dwordx4 stores.
        int g = (b - NROWS / 4) * 4 + wv;
        if (g < NC16) {
            uint2 p[16];
            #pragma unroll
            for (int i = 0; i < 16; ++i) {
                int c = g * 16 + i;
                float4 va = {0.f, 0.f, 0.f, 0.f}, vb = {0.f, 0.f, 0.f, 0.f};
                if (c < NCLS) {
                    const float4* src = (const float4*)(W + (size_t)c * DIM);
                    va = src[lane * 2]; vb = src[lane * 2 + 1];
                }
                float ss = va.x*va.x + va.y*va.y + va.z*va.z + va.w*va.w
                         + vb.x*vb.x + vb.y*vb.y + vb.z*vb.z + vb.w*vb.w;
                ss = wave_reduce_sum(ss);
                float s16 = 16.0f / fmaxf(sqrtf(ss), 1e-12f);
                p[i].x = pk4_fp8(va.x*s16, va.y*s16, va.z*s16, va.w*s16);
                p[i].y = pk4_fp8(vb.x*s16, vb.y*s16, vb.z*s16, vb.w*s16);
            }
            uint8_t* dst = WT + (size_t)g * 8192 + lane * 128;
            #pragma unroll
            for (int j = 0; j < 8; ++j) {
                uint4 q;
                q.x = p[2*j].x;   q.y = p[2*j].y;
                q.z = p[2*j+1].x; q.w = p[2*j+1].y;
                *(uint4*)(dst + j * 16) = q;
            }
        }
    }
}

// --- kernel 2: zero-LDS, zero-barrier register GEMM --------------------------
// 256 blocks (8 mgrp x 32 cgrp), 512 thr, wave = 64M x 64C. A fragments for
// ALL of K register-resident (af[4][16], filled by 64 coalesced 512B loads
// from AnT). Per c-tile x kb: 16 coalesced 512B B-fragment loads from WT
// (L2/L3-resident) + 64 MFMA. No LDS staging, no barriers, no vmcnt
// choreography -- the 2 waves/SIMD free-run and cross-cover L2 latency.
// acc * 2^-8 = cosine (inputs pre-scaled by 16). XCD: all 8 mgrp-blocks of a
// cgrp share b%8 -> same XCD L2 holds that cgrp's B panels (~4.6MB/XCD).
__global__ __launch_bounds__(512) void gemm8_kernel(
        const uint8_t* __restrict__ AnT, const uint8_t* __restrict__ WT,
        float* __restrict__ rowsum) {
    __shared__ float red[128];
    int b = blockIdx.x;
    int mgrp = b >> 5, cgrp = b & 31;
    int tid = threadIdx.x, lane = tid & 63, wv = tid >> 6;

    int wm = (wv >> 2) * 64, wn = (wv & 3) * 64;   // wave = 64M x 64C
    int fr = lane & 15, fq = lane >> 4;

    // ---- A fragments for all of K: 64 coalesced 512B wave-loads
    long af[4][16];
    const uint8_t* ab = AnT + (size_t)(mgrp * 8 + (wm >> 4)) * 8192 + fq * 128 + fr * 8;
    #pragma unroll
    for (int m = 0; m < 4; ++m)
        #pragma unroll
        for (int ksl = 0; ksl < 16; ++ksl)
            af[m][ksl] = *(const long*)(ab + m * 8192 + ksl * 512);

    if (tid < 128) red[tid] = 0.0f;
    __syncthreads();                    // red init visible before tile atomics

    const floatx4 vzero = {0.0f, 0.0f, 0.0f, 0.0f};
    floatx4 acc[4][4] = {};

    int nct = (cgrp < 21) ? 9 : 8;
    int c = cgrp;
    for (int ct = 0; ct < nct; ++ct) {
        // per-thread B fragment base pointers (4 cols owned: n=0..3)
        const uint8_t* bb[4];
        #pragma unroll
        for (int n = 0; n < 4; ++n) {
            int g = min(c * 16 + (wn >> 4) + n, NC16 - 1);  // clamp: masked below
            bb[n] = WT + (size_t)g * 8192 + fq * 128 + fr * 8;
        }
        #pragma unroll
        for (int kb = 0; kb < 4; ++kb) {
            long bg[4][4];
            #pragma unroll
            for (int n = 0; n < 4; ++n)
                #pragma unroll
                for (int ks = 0; ks < 4; ++ks)
                    bg[n][ks] = *(const long*)(bb[n] + kb * 2048 + ks * 512);
            __builtin_amdgcn_s_setprio(1);
            #pragma unroll
            for (int ks = 0; ks < 4; ++ks)
                #pragma unroll
                for (int m = 0; m < 4; ++m)
                    #pragma unroll
                    for (int n = 0; n < 4; ++n)
                        acc[m][n] = __builtin_amdgcn_mfma_f32_16x16x32_fp8_fp8(
                            af[m][kb * 4 + ks], bg[n][ks], acc[m][n], 0, 0, 0);
            __builtin_amdgcn_s_setprio(0);
        }

        // ---- per-tile epilogue: cosine = acc/256; exp(64c-64); reduce
        {
            const float CLIPC = 0.99999950f;  // cos(0.001)
            const float ISCL  = 1.0f / 256.0f;
            int colbase = c * 256 + wn + fr;
            #pragma unroll
            for (int m = 0; m < 4; ++m) {
                #pragma unroll
                for (int reg = 0; reg < 4; ++reg) {
                    float s = 0.0f;
                    #pragma unroll
                    for (int n = 0; n < 4; ++n) {
                        int col = colbase + n * 16;
                        float cc = acc[m][n][reg] * ISCL;
                        cc = fminf(fmaxf(cc, -CLIPC), CLIPC);
                        float term = __expf(64.0f * cc - 64.0f);
                        s += (col < NCLS) ? term : 0.0f;
                    }
                    s += __shfl_xor(s, 1); s += __shfl_xor(s, 2);
                    s += __shfl_xor(s, 4); s += __shfl_xor(s, 8);
                    if (fr == 0) atomicAdd(&red[wm + m * 16 + fq * 4 + reg], s);
                }
            }
            #pragma unroll
            for (int m = 0; m < 4; ++m)
                #pragma unroll
                for (int n = 0; n < 4; ++n)
                    acc[m][n] = vzero;
        }
        c += 32;
    }

    __syncthreads();
    if (tid < 128) atomicAdd(rowsum + mgrp * 128 + tid, red[tid]);
}

// --- kernel 3: batch-stats + margin + log + mean, wave-shuffle reduced ------
__global__ __launch_bounds__(1024) void finalize_kernel(
        const float* __restrict__ rowsum, const float* __restrict__ coslab,
        const float* __restrict__ rownorm, float* __restrict__ out) {
    __shared__ float part[16];
    __shared__ float bc[2];
    int t = threadIdx.x, lane = t & 63, w = t >> 6;
    float v = fminf(fmaxf(rownorm[t], 0.001f), 100.0f);   // safe_norms

    float s = wave_reduce_sum(v);
    if (lane == 0) part[w] = s;
    __syncthreads();
    if (t < 64) {
        float p = (lane < 16) ? part[lane] : 0.0f;
        p = wave_reduce_sum(p);
        if (lane == 0) bc[0] = p * (1.0f / 1024.0f);
    }
    __syncthreads();
    float mean = bc[0];
    float d = v - mean;

    s = wave_reduce_sum(d * d);
    if (lane == 0) part[w] = s;
    __syncthreads();
    if (t < 64) {
        float p = (lane < 16) ? part[lane] : 0.0f;
        p = wave_reduce_sum(p);
        if (lane == 0) bc[1] = sqrtf(p * (1.0f / 1023.0f));  // ddof=1
    }
    __syncthreads();
    float stdv = bc[1];

    float ms = d / (stdv + 0.001f) * 0.333f;
    ms = fminf(fmaxf(ms, -1.0f), 1.0f);
    float g_ang = -0.4f * ms;
    float g_add =  0.4f + 0.4f * ms;
    const float CLIPC = 0.99999950f;
    const float PI = 3.14159265358979323846f;
    float cl  = fminf(fmaxf(coslab[t], -1.0f), 1.0f);
    float cne = fminf(fmaxf(cl, -CLIPC), CLIPC);
    float logit_non = 64.0f * cne;                        // ~ what the GEMM summed
    float theta = acosf(cl);
    float tm = fminf(fmaxf(theta + g_ang, 0.001f), PI - 0.001f);
    float logit_true = (__cosf(tm) - g_add) * 64.0f;
    float ssum = rowsum[t] - __expf(logit_non - 64.0f) + __expf(logit_true - 64.0f);
    float loss = logf(ssum) + 64.0f - logit_true;

    s = wave_reduce_sum(loss);
    if (lane == 0) part[w] = s;
    __syncthreads();
    if (t < 64) {
        float p = (lane < 16) ? part[lane] : 0.0f;
        p = wave_reduce_sum(p);
        if (lane == 0) out[0] = p * (1.0f / 1024.0f);
    }
}

extern "C" void kernel_launch(void* const* d_in, const int* in_sizes, int n_in,
                              void* d_out, int out_size, void* d_ws, size_t ws_size,
                              hipStream_t stream) {
    const float* x      = (const float*)d_in[0];
    const int*   labels = (const int*)d_in[1];
    const float* W      = (const float*)d_in[2];
    float* out = (float*)d_out;
    char* ws = (char*)d_ws;

    // workspace layout (~36.75 MB, same footprint as before)
    const size_t SZ_WT = (size_t)NC16 * 8192;   // 36,216,832: transposed W fp8
    const size_t SZ_AN = 524288;                // 1024*512 fp8 (transposed)
    uint8_t* WT  = (uint8_t*)ws;
    uint8_t* AnT = (uint8_t*)(ws + SZ_WT);
    float* rownorm = (float*)(ws + SZ_WT + SZ_AN);
    float* rowsum  = rownorm + 1024;
    float* coslab  = rowsum + 1024;

    int wblocks = (NC16 + 3) / 4;     // wave per 16-class group
    prep_kernel<<<NROWS / 4 + wblocks, 256, 0, stream>>>(
        x, W, labels, AnT, WT, rownorm, coslab, rowsum);
    gemm8_kernel<<<256, 512, 0, stream>>>(AnT, WT, rowsum);
    finalize_kernel<<<1, 1024, 0, stream>>>(rowsum, coslab, rownorm, out);
}